// Round 1
// baseline (556.546 us; speedup 1.0000x reference)
//
#include <hip/hip_runtime.h>
#include <hip/hip_bf16.h>

typedef __attribute__((ext_vector_type(8))) short bf16x8;
typedef __attribute__((ext_vector_type(4))) float f32x4;

__device__ __forceinline__ ushort f2bf(float x) {
    union { float f; unsigned u; } c; c.f = x;
    unsigned r = c.u + 0x7fff + ((c.u >> 16) & 1);
    return (ushort)(r >> 16);
}

// ---------------- f32 -> bf16 convert (vectorized, grid-stride) ----------------
__global__ void cvt_f32_bf16(const float* __restrict__ in, ushort* __restrict__ out, int n4) {
    int i = blockIdx.x * blockDim.x + threadIdx.x;
    int stride = gridDim.x * blockDim.x;
    for (; i < n4; i += stride) {
        float4 v = ((const float4*)in)[i];
        ushort4 o;
        o.x = f2bf(v.x); o.y = f2bf(v.y); o.z = f2bf(v.z); o.w = f2bf(v.w);
        ((ushort4*)out)[i] = o;
    }
}

// ---------------- bf16 GEMM: C[M,N] = A[M,K] @ Bt[N,K]^T + bias ----------------
// MODE 0: write bf16 into QKV layout [B,H,S,Dk]  (m = b*2048+s, n = h*64+d)
// MODE 1: write f32 into out[m*N+n]
constexpr int BM = 128, BN = 128, BKG = 32, LDP = 40;

template<int MODE>
__global__ __launch_bounds__(256)
void gemm_bt(const ushort* __restrict__ A, const ushort* __restrict__ Bt,
             const float* __restrict__ bias, ushort* __restrict__ outb,
             float* __restrict__ outf, int M, int N, int K) {
    __shared__ ushort As[BM * LDP];
    __shared__ ushort Bs[BN * LDP];
    const int t = threadIdx.x;
    const int lane = t & 63;
    const int wave = t >> 6;
    const int wr = wave >> 1, wc = wave & 1;
    const int l15 = lane & 15, lg = lane >> 4;
    const int m0 = blockIdx.y * BM, n0 = blockIdx.x * BN;

    f32x4 acc[4][4] = {};

    for (int k0 = 0; k0 < K; k0 += BKG) {
#pragma unroll
        for (int i = 0; i < 2; i++) {
            int idx = t + i * 256;
            int row = idx >> 2, col = (idx & 3) * 8;
            *(bf16x8*)&As[row * LDP + col] = *(const bf16x8*)&A[(m0 + row) * K + k0 + col];
            *(bf16x8*)&Bs[row * LDP + col] = *(const bf16x8*)&Bt[(n0 + row) * K + k0 + col];
        }
        __syncthreads();
        bf16x8 af[4], bfr[4];
#pragma unroll
        for (int mi = 0; mi < 4; mi++)
            af[mi] = *(const bf16x8*)&As[(wr * 64 + mi * 16 + l15) * LDP + lg * 8];
#pragma unroll
        for (int ni = 0; ni < 4; ni++)
            bfr[ni] = *(const bf16x8*)&Bs[(wc * 64 + ni * 16 + l15) * LDP + lg * 8];
#pragma unroll
        for (int mi = 0; mi < 4; mi++)
#pragma unroll
            for (int ni = 0; ni < 4; ni++)
                acc[mi][ni] = __builtin_amdgcn_mfma_f32_16x16x32_bf16(af[mi], bfr[ni], acc[mi][ni], 0, 0, 0);
        __syncthreads();
    }

#pragma unroll
    for (int mi = 0; mi < 4; mi++)
#pragma unroll
        for (int ni = 0; ni < 4; ni++)
#pragma unroll
            for (int r = 0; r < 4; r++) {
                int gm = m0 + wr * 64 + mi * 16 + lg * 4 + r;
                int gn = n0 + wc * 64 + ni * 16 + l15;
                float v = acc[mi][ni][r] + bias[gn];
                if (MODE == 0) {
                    int b = gm >> 11, s = gm & 2047, h = gn >> 6, d = gn & 63;
                    outb[(((b << 4) + h) * 2048 + s) * 64 + d] = f2bf(v);
                } else {
                    outf[gm * N + gn] = v;
                }
            }
}

// ---------------- causal flash attention ----------------
// Q,K,V bf16 [B,H,S,64]; out merged bf16 [B,S,1024]
__global__ __launch_bounds__(256)
void attn_fwd(const ushort* __restrict__ Qb, const ushort* __restrict__ Kb,
              const ushort* __restrict__ Vb, ushort* __restrict__ Ab) {
    constexpr int S = 2048, Dk = 64;
    __shared__ ushort Ks[32 * 72];
    __shared__ ushort Vt[64 * 40];
    __shared__ ushort Ps[4][16 * 40];

    const int bh = blockIdx.y;
    const int qt = blockIdx.x;
    const int b = bh >> 4, h = bh & 15;
    const ushort* Qp = Qb + (size_t)bh * S * Dk;
    const ushort* Kp = Kb + (size_t)bh * S * Dk;
    const ushort* Vp = Vb + (size_t)bh * S * Dk;

    const int t = threadIdx.x, lane = t & 63, w = t >> 6;
    const int l15 = lane & 15, lg = lane >> 4;
    const int q0 = qt * 64;
    const int qrow_base = q0 + w * 16;

    // Q fragments (A-layout): row = l15, k = lg*8 (+32 for second frag)
    bf16x8 qf[2];
    qf[0] = *(const bf16x8*)&Qp[(qrow_base + l15) * Dk + lg * 8];
    qf[1] = *(const bf16x8*)&Qp[(qrow_base + l15) * Dk + 32 + lg * 8];

    float mrow[4], lrow[4];
    f32x4 o[4] = {};
#pragma unroll
    for (int r = 0; r < 4; r++) { mrow[r] = -INFINITY; lrow[r] = 0.f; }

    const int nt = (q0 + 64) >> 5;  // number of 32-wide kv tiles (causal)
    for (int tile = 0; tile < nt; tile++) {
        const int k0 = tile << 5;
        {
            int row = t >> 3, col = (t & 7) * 8;
            *(bf16x8*)&Ks[row * 72 + col] = *(const bf16x8*)&Kp[(k0 + row) * Dk + col];
            bf16x8 v = *(const bf16x8*)&Vp[(k0 + row) * Dk + col];
#pragma unroll
            for (int j = 0; j < 8; j++)
                Vt[(col + j) * 40 + row] = (ushort)v[j];
        }
        __syncthreads();

        // scores: 16q x 32kv
        f32x4 sc[2] = {};
#pragma unroll
        for (int nf = 0; nf < 2; nf++)
#pragma unroll
            for (int kb = 0; kb < 2; kb++) {
                bf16x8 kf = *(const bf16x8*)&Ks[(nf * 16 + l15) * 72 + kb * 32 + lg * 8];
                sc[nf] = __builtin_amdgcn_mfma_f32_16x16x32_bf16(qf[kb], kf, sc[nf], 0, 0, 0);
            }

        float p[2][4], alpha[4];
#pragma unroll
        for (int r = 0; r < 4; r++) {
            int q = qrow_base + lg * 4 + r;
            float s0 = sc[0][r] * 0.125f;
            float s1 = sc[1][r] * 0.125f;
            if (k0 + l15 > q)      s0 = -1e30f;
            if (k0 + 16 + l15 > q) s1 = -1e30f;
            float mx = fmaxf(s0, s1);
#pragma unroll
            for (int msk = 1; msk < 16; msk <<= 1) mx = fmaxf(mx, __shfl_xor(mx, msk));
            float mnew = fmaxf(mrow[r], mx);
            float a = __expf(mrow[r] - mnew);
            float p0 = __expf(s0 - mnew), p1 = __expf(s1 - mnew);
            float sum = p0 + p1;
#pragma unroll
            for (int msk = 1; msk < 16; msk <<= 1) sum += __shfl_xor(sum, msk);
            lrow[r] = lrow[r] * a + sum;
            mrow[r] = mnew;
            alpha[r] = a;
            p[0][r] = p0; p[1][r] = p1;
        }
#pragma unroll
        for (int di = 0; di < 4; di++)
#pragma unroll
            for (int r = 0; r < 4; r++) o[di][r] *= alpha[r];

        // P -> LDS (per-wave), then read back in A-fragment layout
#pragma unroll
        for (int nf = 0; nf < 2; nf++)
#pragma unroll
            for (int r = 0; r < 4; r++)
                Ps[w][(lg * 4 + r) * 40 + nf * 16 + l15] = f2bf(p[nf][r]);

        bf16x8 pa = *(const bf16x8*)&Ps[w][l15 * 40 + lg * 8];
#pragma unroll
        for (int di = 0; di < 4; di++) {
            bf16x8 vfr = *(const bf16x8*)&Vt[(di * 16 + l15) * 40 + lg * 8];
            o[di] = __builtin_amdgcn_mfma_f32_16x16x32_bf16(pa, vfr, o[di], 0, 0, 0);
        }
        __syncthreads();
    }

    // normalize + write merged [B,S,1024] bf16
#pragma unroll
    for (int di = 0; di < 4; di++)
#pragma unroll
        for (int r = 0; r < 4; r++) {
            int q = qrow_base + lg * 4 + r;
            float v = o[di][r] / lrow[r];
            int col = h * 64 + di * 16 + l15;
            Ab[((size_t)b * 2048 + q) * 1024 + col] = f2bf(v);
        }
}

// ---------------- launch ----------------
extern "C" void kernel_launch(void* const* d_in, const int* in_sizes, int n_in,
                              void* d_out, int out_size, void* d_ws, size_t ws_size,
                              hipStream_t stream) {
    const float* query = (const float*)d_in[0];
    const float* Wq = (const float*)d_in[2];
    const float* bq = (const float*)d_in[3];
    const float* Wk = (const float*)d_in[4];
    const float* bk = (const float*)d_in[5];
    const float* Wv = (const float*)d_in[6];
    const float* bv = (const float*)d_in[7];
    const float* Wo = (const float*)d_in[8];
    const float* bo = (const float*)d_in[9];
    float* out = (float*)d_out;

    char* ws = (char*)d_ws;
    const size_t SZ_X = 8192ull * 1024 * 2;   // 16 MB bf16
    const size_t SZ_W = 1024ull * 1024 * 2;   // 2 MB bf16
    ushort* Xb  = (ushort*)(ws);
    ushort* Wqb = (ushort*)(ws + SZ_X);
    ushort* Wkb = (ushort*)(ws + SZ_X + SZ_W);
    ushort* Wvb = (ushort*)(ws + SZ_X + 2 * SZ_W);
    ushort* Wob = (ushort*)(ws + SZ_X + 3 * SZ_W);
    ushort* Qb  = (ushort*)(ws + SZ_X + 4 * SZ_W);
    ushort* Kb  = (ushort*)(ws + 2 * SZ_X + 4 * SZ_W);
    ushort* Vb  = (ushort*)(ws + 3 * SZ_X + 4 * SZ_W);
    ushort* Ab  = (ushort*)(ws + 4 * SZ_X + 4 * SZ_W);

    cvt_f32_bf16<<<1024, 256, 0, stream>>>(query, Xb, 8192 * 1024 / 4);
    cvt_f32_bf16<<<256, 256, 0, stream>>>(Wq, Wqb, 1024 * 1024 / 4);
    cvt_f32_bf16<<<256, 256, 0, stream>>>(Wk, Wkb, 1024 * 1024 / 4);
    cvt_f32_bf16<<<256, 256, 0, stream>>>(Wv, Wvb, 1024 * 1024 / 4);
    cvt_f32_bf16<<<256, 256, 0, stream>>>(Wo, Wob, 1024 * 1024 / 4);

    dim3 gg(1024 / BN, 8192 / BM);
    gemm_bt<0><<<gg, 256, 0, stream>>>(Xb, Wqb, bq, Qb, nullptr, 8192, 1024, 1024);
    gemm_bt<0><<<gg, 256, 0, stream>>>(Xb, Wkb, bk, Kb, nullptr, 8192, 1024, 1024);
    gemm_bt<0><<<gg, 256, 0, stream>>>(Xb, Wvb, bv, Vb, nullptr, 8192, 1024, 1024);

    attn_fwd<<<dim3(2048 / 64, 64), 256, 0, stream>>>(Qb, Kb, Vb, Ab);

    gemm_bt<1><<<gg, 256, 0, stream>>>(Ab, Wob, bo, nullptr, out, 8192, 1024, 1024);
}

// Round 2
// 234.562 us; speedup vs baseline: 2.3727x; 2.3727x over previous
//
#include <hip/hip_runtime.h>
#include <hip/hip_bf16.h>

typedef __attribute__((ext_vector_type(8))) short bf16x8;
typedef __attribute__((ext_vector_type(4))) float f32x4;

__device__ __forceinline__ ushort f2bf(float x) {
    union { float f; unsigned u; } c; c.f = x;
    unsigned r = c.u + 0x7fff + ((c.u >> 16) & 1);
    return (ushort)(r >> 16);
}

__device__ __forceinline__ void gload16(const void* g, void* l) {
    __builtin_amdgcn_global_load_lds((const __attribute__((address_space(1))) void*)g,
                                     (__attribute__((address_space(3))) void*)l, 16, 0, 0);
}

// ---------------- f32 -> bf16 convert ----------------
__global__ void cvt_f32_bf16(const float* __restrict__ in, ushort* __restrict__ out, int n4) {
    int i = blockIdx.x * blockDim.x + threadIdx.x;
    int stride = gridDim.x * blockDim.x;
    for (; i < n4; i += stride) {
        float4 v = ((const float4*)in)[i];
        ushort4 o;
        o.x = f2bf(v.x); o.y = f2bf(v.y); o.z = f2bf(v.z); o.w = f2bf(v.w);
        ((ushort4*)out)[i] = o;
    }
}

// ---------------- m97-style bf16 GEMM: C[M,N] = A[M,K] @ Bt[N,K]^T + bias ----------------
// MODE 0: N=3072 QKV-cat -> write bf16 [proj][B,H,S,Dk], bias selected by gn>>10
// MODE 1: write f32 out[gm*N+gn] + bias0
template<int MODE>
__global__ __launch_bounds__(256)
void gemm_m97(const ushort* __restrict__ A, const ushort* __restrict__ Bt,
              const float* __restrict__ bias0, const float* __restrict__ bias1,
              const float* __restrict__ bias2,
              ushort* __restrict__ outb, float* __restrict__ outf,
              int M, int N, int K) {
    __shared__ ushort As[128 * 32];
    __shared__ ushort Bs[128 * 32];
    const int t = threadIdx.x, lane = t & 63, w = t >> 6;
    const int wr = w >> 1, wc = w & 1;
    const int l15 = lane & 15, lg = lane >> 4;
    const int m0 = blockIdx.y * 128, n0 = blockIdx.x * 128;
    const int srow = lane >> 2;                       // 0..15 within 16-row group
    const int sg = (lane & 3) ^ ((lane >> 2) & 3);    // pre-swizzled logical k-block

    f32x4 acc[4][4] = {};

    for (int k0 = 0; k0 < K; k0 += 32) {
#pragma unroll
        for (int i = 0; i < 2; i++) {
            int c = i * 4 + w;                         // 0..7 : 16-row group
            const ushort* as = A + (size_t)(m0 + c * 16 + srow) * K + k0 + sg * 8;
            const ushort* bs = Bt + (size_t)(n0 + c * 16 + srow) * K + k0 + sg * 8;
            gload16(as, &As[c * 512]);
            gload16(bs, &Bs[c * 512]);
        }
        __syncthreads();
        bf16x8 af[4], bfr[4];
#pragma unroll
        for (int mi = 0; mi < 4; mi++) {
            int row = wr * 64 + mi * 16 + l15;
            af[mi] = *(const bf16x8*)&As[row * 32 + ((lg ^ (row & 3)) << 3)];
        }
#pragma unroll
        for (int ni = 0; ni < 4; ni++) {
            int row = wc * 64 + ni * 16 + l15;
            bfr[ni] = *(const bf16x8*)&Bs[row * 32 + ((lg ^ (row & 3)) << 3)];
        }
#pragma unroll
        for (int mi = 0; mi < 4; mi++)
#pragma unroll
            for (int ni = 0; ni < 4; ni++)
                acc[mi][ni] = __builtin_amdgcn_mfma_f32_16x16x32_bf16(af[mi], bfr[ni], acc[mi][ni], 0, 0, 0);
        __syncthreads();
    }

#pragma unroll
    for (int mi = 0; mi < 4; mi++)
#pragma unroll
        for (int ni = 0; ni < 4; ni++)
#pragma unroll
            for (int r = 0; r < 4; r++) {
                int gm = m0 + wr * 64 + mi * 16 + lg * 4 + r;
                int gn = n0 + wc * 64 + ni * 16 + l15;
                if (MODE == 0) {
                    const float* bp = (gn < 1024) ? bias0 : ((gn < 2048) ? bias1 : bias2);
                    float v = acc[mi][ni][r] + bp[gn & 1023];
                    int proj = gn >> 10, nn = gn & 1023;
                    int h = nn >> 6, d = nn & 63;
                    int b = gm >> 11, s = gm & 2047;
                    outb[(size_t)proj * 8388608 + ((((size_t)b << 4) + h) * 2048 + s) * 64 + d] = f2bf(v);
                } else {
                    outf[(size_t)gm * N + gn] = acc[mi][ni][r] + bias0[gn];
                }
            }
}

// ---------------- causal flash attention, KVBLK=64, swapped QK^T ----------------
// block = pair of q-tiles (i, 31-i) => uniform 33 kv-tiles/block
__global__ __launch_bounds__(256)
void attn_fwd(const ushort* __restrict__ Qb, const ushort* __restrict__ Kb,
              const ushort* __restrict__ Vb, ushort* __restrict__ Ab) {
    constexpr int S = 2048;
    __shared__ ushort Ks[64 * 64];
    __shared__ ushort Vt[64 * 64];
    __shared__ ushort Ps[4][16 * 64];

    const int bh = blockIdx.y, b = bh >> 4, h = bh & 15;
    const ushort* Qp = Qb + (size_t)bh * S * 64;
    const ushort* Kp = Kb + (size_t)bh * S * 64;
    const ushort* Vp = Vb + (size_t)bh * S * 64;

    const int t = threadIdx.x, lane = t & 63, w = t >> 6;
    const int l15 = lane & 15, lg = lane >> 4;
    const int psw = (l15 ^ (l15 >> 3)) & 7;   // P row-swizzle (row = l15)

    for (int pass = 0; pass < 2; pass++) {
        const int qt = pass ? (31 - blockIdx.x) : blockIdx.x;
        const int q0 = qt * 64;
        const int nt = qt + 1;

        bf16x8 qf[2];
        qf[0] = *(const bf16x8*)&Qp[(size_t)(q0 + w * 16 + l15) * 64 + lg * 8];
        qf[1] = *(const bf16x8*)&Qp[(size_t)(q0 + w * 16 + l15) * 64 + 32 + lg * 8];

        float m = -3e38f, lsum = 0.f;
        f32x4 o[4] = {};

        for (int tile = 0; tile < nt; tile++) {
            const int k0 = tile * 64;
            // ---- stage K via global_load_lds (swizzled source) ----
#pragma unroll
            for (int i = 0; i < 2; i++) {
                int row = (w * 2 + i) * 8 + (lane >> 3);
                int g = (lane & 7) ^ ((row ^ (row >> 3)) & 7);
                gload16(Kp + (size_t)(k0 + row) * 64 + g * 8, &Ks[(w * 2 + i) * 512]);
            }
            // ---- stage V transposed (swizzled scalar stores) ----
#pragma unroll
            for (int it = 0; it < 2; it++) {
                int kv = (t >> 3) + it * 32;
                int d0 = (t & 7) * 8;
                bf16x8 vv = *(const bf16x8*)&Vp[(size_t)(k0 + kv) * 64 + d0];
#pragma unroll
                for (int j = 0; j < 8; j++) {
                    int d = d0 + j;
                    int p = ((kv >> 3) ^ ((d ^ (d >> 3)) & 7)) & 7;
                    Vt[d * 64 + p * 8 + (kv & 7)] = (ushort)vv[j];
                }
            }
            __syncthreads();

            // ---- QK^T swapped: S^T[kv][q], q = l15 ----
            f32x4 sc[4];
#pragma unroll
            for (int nf = 0; nf < 4; nf++) {
                int row = nf * 16 + l15;
                int sw = (row ^ (row >> 3)) & 7;
                bf16x8 ka = *(const bf16x8*)&Ks[row * 64 + ((lg ^ sw) << 3)];
                bf16x8 kb = *(const bf16x8*)&Ks[row * 64 + (((4 + lg) ^ sw) << 3)];
                f32x4 z = {};
                z = __builtin_amdgcn_mfma_f32_16x16x32_bf16(ka, qf[0], z, 0, 0, 0);
                sc[nf] = __builtin_amdgcn_mfma_f32_16x16x32_bf16(kb, qf[1], z, 0, 0, 0);
            }

            // ---- mask + online softmax (q = l15 lane-local) ----
            const int wq = w * 16 + l15;
            const bool diag = (tile == nt - 1);
            float pv[16];
            float pmax = -3e38f;
#pragma unroll
            for (int nf = 0; nf < 4; nf++)
#pragma unroll
                for (int r = 0; r < 4; r++) {
                    float v = sc[nf][r] * 0.125f;
                    if (diag) { int kvl = nf * 16 + lg * 4 + r; if (kvl > wq) v = -1e30f; }
                    pv[nf * 4 + r] = v;
                    pmax = fmaxf(pmax, v);
                }
            pmax = fmaxf(pmax, __shfl_xor(pmax, 16));
            pmax = fmaxf(pmax, __shfl_xor(pmax, 32));
            if (!__all(pmax <= m + 8.f)) {
                float mnew = fmaxf(m, pmax);
                float a = __expf(m - mnew);
                lsum *= a;
                float ar[4];
#pragma unroll
                for (int r = 0; r < 4; r++) ar[r] = __shfl(a, lg * 4 + r, 16);
#pragma unroll
                for (int di = 0; di < 4; di++)
#pragma unroll
                    for (int r = 0; r < 4; r++) o[di][r] *= ar[r];
                m = mnew;
            }
            float psum = 0.f;
#pragma unroll
            for (int i16 = 0; i16 < 16; i16++) { float e = __expf(pv[i16] - m); psum += e; pv[i16] = e; }
            // P -> LDS (bf16, swizzled), per-wave buffer
#pragma unroll
            for (int nf = 0; nf < 4; nf++)
#pragma unroll
                for (int r = 0; r < 4; r++) {
                    int col = nf * 16 + lg * 4 + r;
                    Ps[w][l15 * 64 + ((((col >> 3) ^ psw) & 7) << 3) + (col & 7)] = f2bf(pv[nf * 4 + r]);
                }
            psum += __shfl_xor(psum, 16);
            psum += __shfl_xor(psum, 32);
            lsum += psum;

            // ---- PV ----
            bf16x8 pa0 = *(const bf16x8*)&Ps[w][l15 * 64 + ((lg ^ psw) << 3)];
            bf16x8 pa1 = *(const bf16x8*)&Ps[w][l15 * 64 + (((4 + lg) ^ psw) << 3)];
#pragma unroll
            for (int di = 0; di < 4; di++) {
                int d = di * 16 + l15;
                int vsw = (d ^ (d >> 3)) & 7;
                bf16x8 v0 = *(const bf16x8*)&Vt[d * 64 + ((lg ^ vsw) << 3)];
                bf16x8 v1 = *(const bf16x8*)&Vt[d * 64 + (((4 + lg) ^ vsw) << 3)];
                o[di] = __builtin_amdgcn_mfma_f32_16x16x32_bf16(pa0, v0, o[di], 0, 0, 0);
                o[di] = __builtin_amdgcn_mfma_f32_16x16x32_bf16(pa1, v1, o[di], 0, 0, 0);
            }
            __syncthreads();
        }

        // ---- normalize + write merged [B,S,1024] ----
        float lr[4];
#pragma unroll
        for (int r = 0; r < 4; r++) lr[r] = __shfl(lsum, lg * 4 + r, 16);
#pragma unroll
        for (int di = 0; di < 4; di++)
#pragma unroll
            for (int r = 0; r < 4; r++) {
                int q = q0 + w * 16 + lg * 4 + r;
                int col = h * 64 + di * 16 + l15;
                Ab[((size_t)b * 2048 + q) * 1024 + col] = f2bf(o[di][r] / lr[r]);
            }
    }
}

// ---------------- launch ----------------
extern "C" void kernel_launch(void* const* d_in, const int* in_sizes, int n_in,
                              void* d_out, int out_size, void* d_ws, size_t ws_size,
                              hipStream_t stream) {
    const float* query = (const float*)d_in[0];
    const float* Wq = (const float*)d_in[2];
    const float* bq = (const float*)d_in[3];
    const float* Wk = (const float*)d_in[4];
    const float* bk = (const float*)d_in[5];
    const float* Wv = (const float*)d_in[6];
    const float* bv = (const float*)d_in[7];
    const float* Wo = (const float*)d_in[8];
    const float* bo = (const float*)d_in[9];
    float* out = (float*)d_out;

    char* ws = (char*)d_ws;
    const size_t SZ_X = 8192ull * 1024 * 2;   // 16 MB bf16
    const size_t SZ_W = 1024ull * 1024 * 2;   // 2 MB bf16
    ushort* Xb   = (ushort*)(ws);
    ushort* Wcat = (ushort*)(ws + SZ_X);                    // [3072,1024] bf16
    ushort* Wob  = (ushort*)(ws + SZ_X + 3 * SZ_W);
    ushort* QKVb = (ushort*)(ws + SZ_X + 4 * SZ_W);         // 3 x 16 MB
    ushort* Ab   = (ushort*)(ws + 4 * SZ_X + 4 * SZ_W);

    cvt_f32_bf16<<<1024, 256, 0, stream>>>(query, Xb, 8192 * 1024 / 4);
    cvt_f32_bf16<<<256, 256, 0, stream>>>(Wq, Wcat, 1024 * 1024 / 4);
    cvt_f32_bf16<<<256, 256, 0, stream>>>(Wk, Wcat + 1048576, 1024 * 1024 / 4);
    cvt_f32_bf16<<<256, 256, 0, stream>>>(Wv, Wcat + 2097152, 1024 * 1024 / 4);
    cvt_f32_bf16<<<256, 256, 0, stream>>>(Wo, Wob, 1024 * 1024 / 4);

    // fused QKV projection: [8192,1024] @ [3072,1024]^T
    gemm_m97<0><<<dim3(3072 / 128, 8192 / 128), 256, 0, stream>>>(
        Xb, Wcat, bq, bk, bv, QKVb, nullptr, 8192, 3072, 1024);

    const ushort* Qb = QKVb;
    const ushort* Kb2 = QKVb + 8388608;
    const ushort* Vb2 = QKVb + 2 * 8388608;
    attn_fwd<<<dim3(16, 64), 256, 0, stream>>>(Qb, Kb2, Vb2, Ab);

    gemm_m97<1><<<dim3(1024 / 128, 8192 / 128), 256, 0, stream>>>(
        Ab, Wob, bo, nullptr, nullptr, nullptr, out, 8192, 1024, 1024);
}

// Round 4
// 198.183 us; speedup vs baseline: 2.8082x; 1.1836x over previous
//
#include <hip/hip_runtime.h>
#include <hip/hip_bf16.h>

typedef __attribute__((ext_vector_type(8))) short bf16x8;
typedef __attribute__((ext_vector_type(4))) float f32x4;
typedef __attribute__((ext_vector_type(2))) unsigned int u32x2;

__device__ __forceinline__ float fexp2(float x) { return __builtin_amdgcn_exp2f(x); }

__device__ __forceinline__ ushort f2bf(float x) {
    union { float f; unsigned u; } c; c.f = x;
    unsigned r = c.u + 0x7fff + ((c.u >> 16) & 1);
    return (ushort)(r >> 16);
}

__device__ __forceinline__ void gload16(const void* g, void* l) {
    __builtin_amdgcn_global_load_lds((const __attribute__((address_space(1))) void*)g,
                                     (__attribute__((address_space(3))) void*)l, 16, 0, 0);
}

// ---------------- f32 -> bf16 converts ----------------
__global__ void cvt_f32_bf16(const float* __restrict__ in, ushort* __restrict__ out, int n4) {
    int i = blockIdx.x * blockDim.x + threadIdx.x;
    int stride = gridDim.x * blockDim.x;
    for (; i < n4; i += stride) {
        float4 v = ((const float4*)in)[i];
        ushort4 o;
        o.x = f2bf(v.x); o.y = f2bf(v.y); o.z = f2bf(v.z); o.w = f2bf(v.w);
        ((ushort4*)out)[i] = o;
    }
}

// 4 weight matrices (1024x1024 f32 each) -> Wcat[3] + Wo bf16, one launch
__global__ void cvt_w4(const float* __restrict__ a, const float* __restrict__ b,
                       const float* __restrict__ c, const float* __restrict__ d,
                       ushort* __restrict__ oq, ushort* __restrict__ ow) {
    const int N4 = 262144;  // float4 per matrix
    int i = blockIdx.x * blockDim.x + threadIdx.x;
    int stride = gridDim.x * blockDim.x;
    for (; i < 4 * N4; i += stride) {
        int sel = i >> 18, local = i & (N4 - 1);
        const float* src = (sel == 0) ? a : (sel == 1) ? b : (sel == 2) ? c : d;
        float4 v = ((const float4*)src)[local];
        ushort4 o;
        o.x = f2bf(v.x); o.y = f2bf(v.y); o.z = f2bf(v.z); o.w = f2bf(v.w);
        if (sel < 3) ((ushort4*)oq)[sel * N4 + local] = o;
        else         ((ushort4*)ow)[local] = o;
    }
}

// ---------------- m97-style bf16 GEMM: C[M,N] = A[M,K] @ Bt[N,K]^T + bias ----------------
template<int MODE>
__global__ __launch_bounds__(256)
void gemm_m97(const ushort* __restrict__ A, const ushort* __restrict__ Bt,
              const float* __restrict__ bias0, const float* __restrict__ bias1,
              const float* __restrict__ bias2,
              ushort* __restrict__ outb, float* __restrict__ outf,
              int M, int N, int K) {
    __shared__ ushort As[128 * 32];
    __shared__ ushort Bs[128 * 32];
    const int t = threadIdx.x, lane = t & 63, w = t >> 6;
    const int wr = w >> 1, wc = w & 1;
    const int l15 = lane & 15, lg = lane >> 4;
    // bijective XCD-chunk swizzle (nwg % 8 == 0 by construction)
    const int nwg = gridDim.x * gridDim.y;
    const int bid = blockIdx.y * gridDim.x + blockIdx.x;
    const int swz = (bid & 7) * (nwg >> 3) + (bid >> 3);
    const int m0 = (swz / gridDim.x) * 128, n0 = (swz % gridDim.x) * 128;
    const int srow = lane >> 2;
    const int sg = (lane & 3) ^ ((lane >> 2) & 3);

    f32x4 acc[4][4] = {};

    for (int k0 = 0; k0 < K; k0 += 32) {
#pragma unroll
        for (int i = 0; i < 2; i++) {
            int c = i * 4 + w;
            const ushort* as = A + (size_t)(m0 + c * 16 + srow) * K + k0 + sg * 8;
            const ushort* bs = Bt + (size_t)(n0 + c * 16 + srow) * K + k0 + sg * 8;
            gload16(as, &As[c * 512]);
            gload16(bs, &Bs[c * 512]);
        }
        __syncthreads();
        bf16x8 af[4], bfr[4];
#pragma unroll
        for (int mi = 0; mi < 4; mi++) {
            int row = wr * 64 + mi * 16 + l15;
            af[mi] = *(const bf16x8*)&As[row * 32 + ((lg ^ (row & 3)) << 3)];
        }
#pragma unroll
        for (int ni = 0; ni < 4; ni++) {
            int row = wc * 64 + ni * 16 + l15;
            bfr[ni] = *(const bf16x8*)&Bs[row * 32 + ((lg ^ (row & 3)) << 3)];
        }
        __builtin_amdgcn_s_setprio(1);
#pragma unroll
        for (int mi = 0; mi < 4; mi++)
#pragma unroll
            for (int ni = 0; ni < 4; ni++)
                acc[mi][ni] = __builtin_amdgcn_mfma_f32_16x16x32_bf16(af[mi], bfr[ni], acc[mi][ni], 0, 0, 0);
        __builtin_amdgcn_s_setprio(0);
        __syncthreads();
    }

#pragma unroll
    for (int mi = 0; mi < 4; mi++)
#pragma unroll
        for (int ni = 0; ni < 4; ni++)
#pragma unroll
            for (int r = 0; r < 4; r++) {
                int gm = m0 + wr * 64 + mi * 16 + lg * 4 + r;
                int gn = n0 + wc * 64 + ni * 16 + l15;
                if (MODE == 0) {
                    const float* bp = (gn < 1024) ? bias0 : ((gn < 2048) ? bias1 : bias2);
                    float v = acc[mi][ni][r] + bp[gn & 1023];
                    int proj = gn >> 10, nn = gn & 1023;
                    int h = nn >> 6, d = nn & 63;
                    int b = gm >> 11, s = gm & 2047;
                    outb[(size_t)proj * 8388608 + ((((size_t)b << 4) + h) * 2048 + s) * 64 + d] = f2bf(v);
                } else {
                    outf[(size_t)gm * N + gn] = acc[mi][ni][r] + bias0[gn];
                }
            }
}

// ---------------- causal flash attention ----------------
// KVBLK=64, swapped QK^T, dbuf K/V + async global_load_lds, tr_b16 V reads.
// block = q-tile pair (i, 31-i) => uniform 33 kv-tiles.
__global__ __launch_bounds__(256, 4)
void attn_fwd(const ushort* __restrict__ Qb, const ushort* __restrict__ Kb,
              const ushort* __restrict__ Vb, ushort* __restrict__ Ab) {
    constexpr int S = 2048;
    // elems: Ks[2][4096] @0, Vt[2][4096] @8192, Ps[4][1024] @16384
    __shared__ ushort lds[20480];

    const int bh = blockIdx.y, b = bh >> 4, h = bh & 15;
    const ushort* Qp = Qb + (size_t)bh * S * 64;
    const ushort* Kp = Kb + (size_t)bh * S * 64;
    const ushort* Vp = Vb + (size_t)bh * S * 64;

    const int t = threadIdx.x, lane = t & 63, w = t >> 6;
    const int l15 = lane & 15, lg = lane >> 4;
    const int psw = (l15 ^ (l15 >> 3)) & 7;

    // --- precomputed staging offsets (elems within a 64x64 tile) ---
    int koff[2], voff[2];
#pragma unroll
    for (int i = 0; i < 2; i++) {
        int row = (w * 2 + i) * 8 + (lane >> 3);
        int g = (lane & 7) ^ ((row ^ (row >> 3)) & 7);
        koff[i] = row * 64 + g * 8;
    }
#pragma unroll
    for (int it = 0; it < 2; it++) {
        int L = (it * 4 + w) * 64 + lane;
        int kvb = L >> 5, db = (L >> 3) & 3, kvr = (L >> 1) & 3, dh = L & 1;
        voff[it] = (kvb * 4 + kvr) * 64 + db * 16 + dh * 8;
    }
    const unsigned vtbase = (unsigned)(uintptr_t)&lds[8192] + (lg << 10) + (l15 << 3);

    auto stage = [&](int phase, int k0) {
#pragma unroll
        for (int i = 0; i < 2; i++)
            gload16(Kp + (size_t)k0 * 64 + koff[i], &lds[(phase << 12) + ((w * 2 + i) << 9)]);
#pragma unroll
        for (int it = 0; it < 2; it++)
            gload16(Vp + (size_t)k0 * 64 + voff[it], &lds[8192 + (phase << 12) + (((it << 2) + w) << 9)]);
    };

    constexpr float SCALE = 0.125f * 1.44269504088896f;  // exp2 domain

    for (int pass = 0; pass < 2; pass++) {
        const int qt = pass ? (31 - blockIdx.x) : blockIdx.x;
        const int q0 = qt * 64;
        const int nt = qt + 1;

        bf16x8 qf[2];
        qf[0] = *(const bf16x8*)&Qp[(size_t)(q0 + w * 16 + l15) * 64 + lg * 8];
        qf[1] = *(const bf16x8*)&Qp[(size_t)(q0 + w * 16 + l15) * 64 + 32 + lg * 8];

        float m = -3e38f, lsum = 0.f;
        f32x4 o[4] = {};

        __syncthreads();
        stage(0, 0);

        for (int tile = 0; tile < nt; tile++) {
            const int phase = tile & 1;
            if (tile + 1 < nt) {
                stage(phase ^ 1, (tile + 1) * 64);
                asm volatile("s_waitcnt vmcnt(4)" ::: "memory");
            } else {
                asm volatile("s_waitcnt vmcnt(0)" ::: "memory");
            }
            __syncthreads();

            // ---- QK^T swapped: S^T[kv][q], q = l15 ----
            const ushort* Kcur = &lds[phase << 12];
            f32x4 sc[4];
            __builtin_amdgcn_s_setprio(1);
#pragma unroll
            for (int nf = 0; nf < 4; nf++) {
                int row = nf * 16 + l15;
                int sw = (row ^ (row >> 3)) & 7;
                bf16x8 ka = *(const bf16x8*)&Kcur[row * 64 + ((lg ^ sw) << 3)];
                bf16x8 kb = *(const bf16x8*)&Kcur[row * 64 + (((4 + lg) ^ sw) << 3)];
                f32x4 z = {};
                z = __builtin_amdgcn_mfma_f32_16x16x32_bf16(ka, qf[0], z, 0, 0, 0);
                sc[nf] = __builtin_amdgcn_mfma_f32_16x16x32_bf16(kb, qf[1], z, 0, 0, 0);
            }
            __builtin_amdgcn_s_setprio(0);

            // ---- mask + online softmax (exp2 domain, q = l15 lane-local) ----
            const int wq = w * 16 + l15;
            const bool diag = (tile == nt - 1);
            float pv[16];
            float pmax = -3e38f;
#pragma unroll
            for (int nf = 0; nf < 4; nf++)
#pragma unroll
                for (int r = 0; r < 4; r++) {
                    float v = sc[nf][r] * SCALE;
                    if (diag) { int kvl = nf * 16 + lg * 4 + r; if (kvl > wq) v = -1e30f; }
                    pv[nf * 4 + r] = v;
                    pmax = fmaxf(pmax, v);
                }
            pmax = fmaxf(pmax, __shfl_xor(pmax, 16));
            pmax = fmaxf(pmax, __shfl_xor(pmax, 32));
            if (!__all(pmax <= m + 8.f)) {
                float mnew = fmaxf(m, pmax);
                float a = fexp2(m - mnew);
                lsum *= a;
                float ar[4];
#pragma unroll
                for (int r = 0; r < 4; r++) ar[r] = __shfl(a, lg * 4 + r, 16);
#pragma unroll
                for (int di = 0; di < 4; di++)
#pragma unroll
                    for (int r = 0; r < 4; r++) o[di][r] *= ar[r];
                m = mnew;
            }
            float psum = 0.f;
#pragma unroll
            for (int i16 = 0; i16 < 16; i16++) { float e = fexp2(pv[i16] - m); psum += e; pv[i16] = e; }
            ushort* Pw = &lds[16384 + (w << 10)];
#pragma unroll
            for (int nf = 0; nf < 4; nf++)
#pragma unroll
                for (int r = 0; r < 4; r++) {
                    int col = nf * 16 + lg * 4 + r;
                    Pw[l15 * 64 + ((((col >> 3) ^ psw) & 7) << 3) + (col & 7)] = f2bf(pv[nf * 4 + r]);
                }
            psum += __shfl_xor(psum, 16);
            psum += __shfl_xor(psum, 32);
            lsum += psum;

            // ---- PV: A = P (LDS roundtrip), B = V via ds_read_b64_tr_b16 ----
            bf16x8 pa0 = *(const bf16x8*)&Pw[l15 * 64 + ((lg ^ psw) << 3)];
            bf16x8 pa1 = *(const bf16x8*)&Pw[l15 * 64 + (((4 + lg) ^ psw) << 3)];

            const unsigned vtb = vtbase + (phase << 13);
            u32x2 vr[4][4];
#define TRR(dst, OFFSTR) asm volatile("ds_read_b64_tr_b16 %0, %1 offset:" OFFSTR : "=v"(dst) : "v"(vtb))
            TRR(vr[0][0], "0");   TRR(vr[0][1], "512"); TRR(vr[0][2], "4096"); TRR(vr[0][3], "4608");
            TRR(vr[1][0], "128"); TRR(vr[1][1], "640"); TRR(vr[1][2], "4224"); TRR(vr[1][3], "4736");
            TRR(vr[2][0], "256"); TRR(vr[2][1], "768"); TRR(vr[2][2], "4352"); TRR(vr[2][3], "4864");
            TRR(vr[3][0], "384"); TRR(vr[3][1], "896"); TRR(vr[3][2], "4480"); TRR(vr[3][3], "4992");
#undef TRR
            asm volatile("s_waitcnt lgkmcnt(0)" ::: "memory");
            __builtin_amdgcn_sched_barrier(0);

            union FragU { bf16x8 v; u32x2 h[2]; };
            __builtin_amdgcn_s_setprio(1);
#pragma unroll
            for (int di = 0; di < 4; di++) {
                FragU f0, f1;
                f0.h[0] = vr[di][0]; f0.h[1] = vr[di][1];
                f1.h[0] = vr[di][2]; f1.h[1] = vr[di][3];
                o[di] = __builtin_amdgcn_mfma_f32_16x16x32_bf16(pa0, f0.v, o[di], 0, 0, 0);
                o[di] = __builtin_amdgcn_mfma_f32_16x16x32_bf16(pa1, f1.v, o[di], 0, 0, 0);
            }
            __builtin_amdgcn_s_setprio(0);
            __syncthreads();
        }

        // ---- normalize + write merged [B,S,1024] ----
        float lr[4];
#pragma unroll
        for (int r = 0; r < 4; r++) lr[r] = __shfl(lsum, lg * 4 + r, 16);
#pragma unroll
        for (int di = 0; di < 4; di++)
#pragma unroll
            for (int r = 0; r < 4; r++) {
                int q = q0 + w * 16 + lg * 4 + r;
                int col = h * 64 + di * 16 + l15;
                Ab[((size_t)b * 2048 + q) * 1024 + col] = f2bf(o[di][r] / lr[r]);
            }
    }
}

// ---------------- launch ----------------
extern "C" void kernel_launch(void* const* d_in, const int* in_sizes, int n_in,
                              void* d_out, int out_size, void* d_ws, size_t ws_size,
                              hipStream_t stream) {
    const float* query = (const float*)d_in[0];
    const float* Wq = (const float*)d_in[2];
    const float* bq = (const float*)d_in[3];
    const float* Wk = (const float*)d_in[4];
    const float* bk = (const float*)d_in[5];
    const float* Wv = (const float*)d_in[6];
    const float* bv = (const float*)d_in[7];
    const float* Wo = (const float*)d_in[8];
    const float* bo = (const float*)d_in[9];
    float* out = (float*)d_out;

    char* ws = (char*)d_ws;
    const size_t SZ_X = 8192ull * 1024 * 2;
    const size_t SZ_W = 1024ull * 1024 * 2;
    ushort* Xb   = (ushort*)(ws);
    ushort* Wcat = (ushort*)(ws + SZ_X);
    ushort* Wob  = (ushort*)(ws + SZ_X + 3 * SZ_W);
    ushort* QKVb = (ushort*)(ws + SZ_X + 4 * SZ_W);
    ushort* Ab   = (ushort*)(ws + 4 * SZ_X + 4 * SZ_W);

    cvt_f32_bf16<<<1024, 256, 0, stream>>>(query, Xb, 8192 * 1024 / 4);
    cvt_w4<<<1024, 256, 0, stream>>>(Wq, Wk, Wv, Wo, Wcat, Wob);

    gemm_m97<0><<<dim3(3072 / 128, 8192 / 128), 256, 0, stream>>>(
        Xb, Wcat, bq, bk, bv, QKVb, nullptr, 8192, 3072, 1024);

    attn_fwd<<<dim3(16, 64), 256, 0, stream>>>(QKVb, QKVb + 8388608, QKVb + 2 * 8388608, Ab);

    gemm_m97<1><<<dim3(1024 / 128, 8192 / 128), 256, 0, stream>>>(
        Ab, Wob, bo, nullptr, nullptr, nullptr, out, 8192, 1024, 1024);
}

// Round 5
// 189.017 us; speedup vs baseline: 2.9444x; 1.0485x over previous
//
#include <hip/hip_runtime.h>
#include <hip/hip_bf16.h>

typedef __attribute__((ext_vector_type(8))) short bf16x8;
typedef __attribute__((ext_vector_type(4))) float f32x4;
typedef __attribute__((ext_vector_type(2))) unsigned int u32x2;

__device__ __forceinline__ float fexp2(float x) { return __builtin_amdgcn_exp2f(x); }

__device__ __forceinline__ ushort f2bf(float x) {
    union { float f; unsigned u; } c; c.f = x;
    unsigned r = c.u + 0x7fff + ((c.u >> 16) & 1);
    return (ushort)(r >> 16);
}

__device__ __forceinline__ unsigned cvtpk(float lo, float hi) {
    unsigned r;
    asm("v_cvt_pk_bf16_f32 %0, %1, %2" : "=v"(r) : "v"(lo), "v"(hi));
    return r;
}

__device__ __forceinline__ void gload16(const void* g, void* l) {
    __builtin_amdgcn_global_load_lds((const __attribute__((address_space(1))) void*)g,
                                     (__attribute__((address_space(3))) void*)l, 16, 0, 0);
}

__device__ __forceinline__ void blockbar() {
    asm volatile("" ::: "memory");
    __builtin_amdgcn_s_barrier();
    asm volatile("" ::: "memory");
}

// ---------------- f32 -> bf16 converts ----------------
__global__ void cvt_f32_bf16(const float* __restrict__ in, ushort* __restrict__ out, int n4) {
    int i = blockIdx.x * blockDim.x + threadIdx.x;
    int stride = gridDim.x * blockDim.x;
    for (; i < n4; i += stride) {
        float4 v = ((const float4*)in)[i];
        ushort4 o;
        o.x = f2bf(v.x); o.y = f2bf(v.y); o.z = f2bf(v.z); o.w = f2bf(v.w);
        ((ushort4*)out)[i] = o;
    }
}

__global__ void cvt_w4(const float* __restrict__ a, const float* __restrict__ b,
                       const float* __restrict__ c, const float* __restrict__ d,
                       ushort* __restrict__ oq, ushort* __restrict__ ow) {
    const int N4 = 262144;
    int i = blockIdx.x * blockDim.x + threadIdx.x;
    int stride = gridDim.x * blockDim.x;
    for (; i < 4 * N4; i += stride) {
        int sel = i >> 18, local = i & (N4 - 1);
        const float* src = (sel == 0) ? a : (sel == 1) ? b : (sel == 2) ? c : d;
        float4 v = ((const float4*)src)[local];
        ushort4 o;
        o.x = f2bf(v.x); o.y = f2bf(v.y); o.z = f2bf(v.z); o.w = f2bf(v.w);
        if (sel < 3) ((ushort4*)oq)[sel * N4 + local] = o;
        else         ((ushort4*)ow)[local] = o;
    }
}

// ---------------- m97-style bf16 GEMM ----------------
template<int MODE>
__global__ __launch_bounds__(256)
void gemm_m97(const ushort* __restrict__ A, const ushort* __restrict__ Bt,
              const float* __restrict__ bias0, const float* __restrict__ bias1,
              const float* __restrict__ bias2,
              ushort* __restrict__ outb, float* __restrict__ outf,
              int M, int N, int K) {
    __shared__ ushort As[128 * 32];
    __shared__ ushort Bs[128 * 32];
    const int t = threadIdx.x, lane = t & 63, w = t >> 6;
    const int wr = w >> 1, wc = w & 1;
    const int l15 = lane & 15, lg = lane >> 4;
    const int nwg = gridDim.x * gridDim.y;
    const int bid = blockIdx.y * gridDim.x + blockIdx.x;
    const int swz = (bid & 7) * (nwg >> 3) + (bid >> 3);
    const int m0 = (swz / gridDim.x) * 128, n0 = (swz % gridDim.x) * 128;
    const int srow = lane >> 2;
    const int sg = (lane & 3) ^ ((lane >> 2) & 3);

    f32x4 acc[4][4] = {};

    for (int k0 = 0; k0 < K; k0 += 32) {
#pragma unroll
        for (int i = 0; i < 2; i++) {
            int c = i * 4 + w;
            const ushort* as = A + (size_t)(m0 + c * 16 + srow) * K + k0 + sg * 8;
            const ushort* bs = Bt + (size_t)(n0 + c * 16 + srow) * K + k0 + sg * 8;
            gload16(as, &As[c * 512]);
            gload16(bs, &Bs[c * 512]);
        }
        __syncthreads();
        bf16x8 af[4], bfr[4];
#pragma unroll
        for (int mi = 0; mi < 4; mi++) {
            int row = wr * 64 + mi * 16 + l15;
            af[mi] = *(const bf16x8*)&As[row * 32 + ((lg ^ (row & 3)) << 3)];
        }
#pragma unroll
        for (int ni = 0; ni < 4; ni++) {
            int row = wc * 64 + ni * 16 + l15;
            bfr[ni] = *(const bf16x8*)&Bs[row * 32 + ((lg ^ (row & 3)) << 3)];
        }
        __builtin_amdgcn_s_setprio(1);
#pragma unroll
        for (int mi = 0; mi < 4; mi++)
#pragma unroll
            for (int ni = 0; ni < 4; ni++)
                acc[mi][ni] = __builtin_amdgcn_mfma_f32_16x16x32_bf16(af[mi], bfr[ni], acc[mi][ni], 0, 0, 0);
        __builtin_amdgcn_s_setprio(0);
        __syncthreads();
    }

#pragma unroll
    for (int mi = 0; mi < 4; mi++)
#pragma unroll
        for (int ni = 0; ni < 4; ni++)
#pragma unroll
            for (int r = 0; r < 4; r++) {
                int gm = m0 + wr * 64 + mi * 16 + lg * 4 + r;
                int gn = n0 + wc * 64 + ni * 16 + l15;
                if (MODE == 0) {
                    const float* bp = (gn < 1024) ? bias0 : ((gn < 2048) ? bias1 : bias2);
                    float v = acc[mi][ni][r] + bp[gn & 1023];
                    int proj = gn >> 10, nn = gn & 1023;
                    int h = nn >> 6, d = nn & 63;
                    int b = gm >> 11, s = gm & 2047;
                    outb[(size_t)proj * 8388608 + ((((size_t)b << 4) + h) * 2048 + s) * 64 + d] = f2bf(v);
                } else {
                    outf[(size_t)gm * N + gn] = acc[mi][ni][r] + bias0[gn];
                }
            }
}

// ---------------- causal flash attention ----------------
// 128-row q-tiles (32 q/wave, 2 frags), KVBLK=64, swapped QK^T, dbuf async staging,
// counted vmcnt across raw barriers, tr_b16 V reads, cvt_pk+b64 P path.
// XCD-grouped: bh = x*8 + (y&7) so one head's 8 blocks share an XCD L2.
__global__ __launch_bounds__(256, 2)
void attn_fwd(const ushort* __restrict__ Qb, const ushort* __restrict__ Kb,
              const ushort* __restrict__ Vb, ushort* __restrict__ Ab) {
    constexpr int S = 2048;
    // ushorts: K[2][4096] @0, V[2][4096] @8192, P[4][2][1024] @16384  (48KB)
    __shared__ ushort lds[24576];

    const int bh = blockIdx.x * 8 + (blockIdx.y & 7);
    const int qpair = blockIdx.y >> 3;
    const int b = bh >> 4, h = bh & 15;
    const ushort* Qp = Qb + (size_t)bh * S * 64;
    const ushort* Kp = Kb + (size_t)bh * S * 64;
    const ushort* Vp = Vb + (size_t)bh * S * 64;

    const int t = threadIdx.x, lane = t & 63, w = t >> 6;
    const int l15 = lane & 15, lg = lane >> 4;

    // staging offsets (elems within a 64x64 tile)
    int koff[2], voff[2];
#pragma unroll
    for (int i = 0; i < 2; i++) {
        int row = (w * 2 + i) * 8 + (lane >> 3);
        int g = (lane & 7) ^ ((row ^ (row >> 3)) & 7);
        koff[i] = row * 64 + g * 8;
    }
#pragma unroll
    for (int it = 0; it < 2; it++) {
        int L = (it * 4 + w) * 64 + lane;
        int kvb = L >> 5, db = (L >> 3) & 3, kvr = (L >> 1) & 3, dh = L & 1;
        voff[it] = (kvb * 4 + kvr) * 64 + db * 16 + dh * 8;
    }
    const unsigned vtbase = (unsigned)(uintptr_t)&lds[8192] + (lg << 10) + (l15 << 3);

    auto stage = [&](int phase, int k0) {
#pragma unroll
        for (int i = 0; i < 2; i++)
            gload16(Kp + (size_t)k0 * 64 + koff[i], &lds[(phase << 12) + ((w * 2 + i) << 9)]);
#pragma unroll
        for (int it = 0; it < 2; it++)
            gload16(Vp + (size_t)k0 * 64 + voff[it], &lds[8192 + (phase << 12) + (((it << 2) + w) << 9)]);
    };

    constexpr float SCALE = 0.125f * 1.44269504088896f;  // exp2 domain
    ushort* Pwf[2] = { &lds[16384 + ((w * 2 + 0) << 10)], &lds[16384 + ((w * 2 + 1) << 10)] };
    const int rsw = l15 & 7;  // P layout swizzle: phys block = cb ^ rsw

    for (int pass = 0; pass < 2; pass++) {
        const int qt = pass ? (15 - qpair) : qpair;
        const int q0 = qt * 128;
        const int nt = 2 * qt + 2;
        const int fb0 = q0 + w * 32;  // frag0 global q base

        bf16x8 qf[2][2];
#pragma unroll
        for (int f = 0; f < 2; f++) {
            qf[f][0] = *(const bf16x8*)&Qp[(size_t)(fb0 + f * 16 + l15) * 64 + lg * 8];
            qf[f][1] = *(const bf16x8*)&Qp[(size_t)(fb0 + f * 16 + l15) * 64 + 32 + lg * 8];
        }

        float mx[2] = { -3e38f, -3e38f }, ls[2] = { 0.f, 0.f };
        f32x4 o[2][4] = {};

        blockbar();
        stage(0, 0);

        for (int tile = 0; tile < nt; tile++) {
            const int phase = tile & 1;
            const int k0 = tile * 64;
            if (tile + 1 < nt) {
                stage(phase ^ 1, (tile + 1) * 64);
                asm volatile("s_waitcnt vmcnt(4)" ::: "memory");
            } else {
                asm volatile("s_waitcnt vmcnt(0)" ::: "memory");
            }
            blockbar();

            if (k0 <= fb0 + 31) {  // wave-uniform causal skip
                const ushort* Kcur = &lds[phase << 12];
                bf16x8 ka[4], kb[4];
#pragma unroll
                for (int nf = 0; nf < 4; nf++) {
                    int row = nf * 16 + l15;
                    int sw = (row ^ (row >> 3)) & 7;
                    ka[nf] = *(const bf16x8*)&Kcur[row * 64 + ((lg ^ sw) << 3)];
                    kb[nf] = *(const bf16x8*)&Kcur[row * 64 + (((4 + lg) ^ sw) << 3)];
                }
                f32x4 sc[2][4];
                __builtin_amdgcn_s_setprio(1);
#pragma unroll
                for (int f = 0; f < 2; f++)
#pragma unroll
                    for (int nf = 0; nf < 4; nf++) {
                        f32x4 z = {};
                        z = __builtin_amdgcn_mfma_f32_16x16x32_bf16(ka[nf], qf[f][0], z, 0, 0, 0);
                        sc[f][nf] = __builtin_amdgcn_mfma_f32_16x16x32_bf16(kb[nf], qf[f][1], z, 0, 0, 0);
                    }
                __builtin_amdgcn_s_setprio(0);

                u32x2 vr[4][4];
                const unsigned vtb = vtbase + (phase << 13);

#pragma unroll
                for (int f = 0; f < 2; f++) {
                    const int fbg = fb0 + f * 16;
                    const int wq = fbg + l15;
                    const bool diag = (k0 + 64 > fbg);
                    float pv[16];
                    float pmax = -3e38f;
#pragma unroll
                    for (int nf = 0; nf < 4; nf++)
#pragma unroll
                        for (int r = 0; r < 4; r++) {
                            float v = sc[f][nf][r] * SCALE;
                            if (diag) { int kvg = k0 + nf * 16 + lg * 4 + r; if (kvg > wq) v = -1e30f; }
                            pv[nf * 4 + r] = v;
                            pmax = fmaxf(pmax, v);
                        }
                    pmax = fmaxf(pmax, __shfl_xor(pmax, 16));
                    pmax = fmaxf(pmax, __shfl_xor(pmax, 32));
                    if (!__all(pmax <= mx[f] + 8.f)) {
                        float mnew = fmaxf(mx[f], pmax);
                        float a = fexp2(mx[f] - mnew);
                        ls[f] *= a;
                        float ar[4];
#pragma unroll
                        for (int r = 0; r < 4; r++) ar[r] = __shfl(a, lg * 4 + r, 16);
#pragma unroll
                        for (int di = 0; di < 4; di++)
#pragma unroll
                            for (int r = 0; r < 4; r++) o[f][di][r] *= ar[r];
                        mx[f] = mnew;
                    }
                    float psum = 0.f;
#pragma unroll
                    for (int i16 = 0; i16 < 16; i16++) { float e = fexp2(pv[i16] - mx[f]); psum += e; pv[i16] = e; }
                    // pack + 4x ds_write_b64 (even bank spread)
#pragma unroll
                    for (int nf = 0; nf < 4; nf++) {
                        u32x2 d;
                        d.x = cvtpk(pv[nf * 4 + 0], pv[nf * 4 + 1]);
                        d.y = cvtpk(pv[nf * 4 + 2], pv[nf * 4 + 3]);
                        int bp = (nf * 2 + (lg >> 1)) ^ rsw;
                        *(u32x2*)&Pwf[f][l15 * 64 + bp * 8 + ((lg & 1) << 2)] = d;
                    }
                    psum += __shfl_xor(psum, 16);
                    psum += __shfl_xor(psum, 32);
                    ls[f] += psum;

                    if (f == 0) {  // issue V tr-reads; latency hides under frag1 softmax
#define TRR(dst, OFFSTR) asm volatile("ds_read_b64_tr_b16 %0, %1 offset:" OFFSTR : "=v"(dst) : "v"(vtb))
                        TRR(vr[0][0], "0");   TRR(vr[0][1], "512"); TRR(vr[0][2], "4096"); TRR(vr[0][3], "4608");
                        TRR(vr[1][0], "128"); TRR(vr[1][1], "640"); TRR(vr[1][2], "4224"); TRR(vr[1][3], "4736");
                        TRR(vr[2][0], "256"); TRR(vr[2][1], "768"); TRR(vr[2][2], "4352"); TRR(vr[2][3], "4864");
                        TRR(vr[3][0], "384"); TRR(vr[3][1], "896"); TRR(vr[3][2], "4480"); TRR(vr[3][3], "4992");
#undef TRR
                    }
                }

                asm volatile("s_waitcnt lgkmcnt(0)" ::: "memory");
                __builtin_amdgcn_sched_barrier(0);

                bf16x8 pa[2][2];
#pragma unroll
                for (int f = 0; f < 2; f++) {
                    pa[f][0] = *(const bf16x8*)&Pwf[f][l15 * 64 + ((lg ^ rsw) << 3)];
                    pa[f][1] = *(const bf16x8*)&Pwf[f][l15 * 64 + (((4 + lg) ^ rsw) << 3)];
                }
                union FragU { bf16x8 v; u32x2 h[2]; };
                __builtin_amdgcn_s_setprio(1);
#pragma unroll
                for (int di = 0; di < 4; di++) {
                    FragU f0, f1;
                    f0.h[0] = vr[di][0]; f0.h[1] = vr[di][1];
                    f1.h[0] = vr[di][2]; f1.h[1] = vr[di][3];
#pragma unroll
                    for (int f = 0; f < 2; f++) {
                        o[f][di] = __builtin_amdgcn_mfma_f32_16x16x32_bf16(pa[f][0], f0.v, o[f][di], 0, 0, 0);
                        o[f][di] = __builtin_amdgcn_mfma_f32_16x16x32_bf16(pa[f][1], f1.v, o[f][di], 0, 0, 0);
                    }
                }
                __builtin_amdgcn_s_setprio(0);
            }
            blockbar();
        }

        // normalize + write merged [B,S,1024]
#pragma unroll
        for (int f = 0; f < 2; f++) {
            float inv[4];
#pragma unroll
            for (int r = 0; r < 4; r++)
                inv[r] = __builtin_amdgcn_rcpf(__shfl(ls[f], lg * 4 + r, 16));
#pragma unroll
            for (int di = 0; di < 4; di++)
#pragma unroll
                for (int r = 0; r < 4; r++) {
                    int q = fb0 + f * 16 + lg * 4 + r;
                    int col = h * 64 + di * 16 + l15;
                    Ab[((size_t)b * 2048 + q) * 1024 + col] = f2bf(o[f][di][r] * inv[r]);
                }
        }
    }
}

// ---------------- launch ----------------
extern "C" void kernel_launch(void* const* d_in, const int* in_sizes, int n_in,
                              void* d_out, int out_size, void* d_ws, size_t ws_size,
                              hipStream_t stream) {
    const float* query = (const float*)d_in[0];
    const float* Wq = (const float*)d_in[2];
    const float* bq = (const float*)d_in[3];
    const float* Wk = (const float*)d_in[4];
    const float* bk = (const float*)d_in[5];
    const float* Wv = (const float*)d_in[6];
    const float* bv = (const float*)d_in[7];
    const float* Wo = (const float*)d_in[8];
    const float* bo = (const float*)d_in[9];
    float* out = (float*)d_out;

    char* ws = (char*)d_ws;
    const size_t SZ_X = 8192ull * 1024 * 2;
    const size_t SZ_W = 1024ull * 1024 * 2;
    ushort* Xb   = (ushort*)(ws);
    ushort* Wcat = (ushort*)(ws + SZ_X);
    ushort* Wob  = (ushort*)(ws + SZ_X + 3 * SZ_W);
    ushort* QKVb = (ushort*)(ws + SZ_X + 4 * SZ_W);
    ushort* Ab   = (ushort*)(ws + 4 * SZ_X + 4 * SZ_W);

    cvt_f32_bf16<<<1024, 256, 0, stream>>>(query, Xb, 8192 * 1024 / 4);
    cvt_w4<<<1024, 256, 0, stream>>>(Wq, Wk, Wv, Wo, Wcat, Wob);

    gemm_m97<0><<<dim3(3072 / 128, 8192 / 128), 256, 0, stream>>>(
        Xb, Wcat, bq, bk, bv, QKVb, nullptr, 8192, 3072, 1024);

    attn_fwd<<<dim3(8, 64), 256, 0, stream>>>(QKVb, QKVb + 8388608, QKVb + 2 * 8388608, Ab);

    gemm_m97<1><<<dim3(1024 / 128, 8192 / 128), 256, 0, stream>>>(
        Ab, Wob, bo, nullptr, nullptr, nullptr, out, 8192, 1024, 1024);
}